// Round 2
// baseline (687.928 us; speedup 1.0000x reference)
//
#include <hip/hip_runtime.h>
#include <stdint.h>

#define DEV __device__ __forceinline__

typedef float f32x4 __attribute__((ext_vector_type(4)));
typedef short s16x8 __attribute__((ext_vector_type(8)));
typedef unsigned int u32x4 __attribute__((ext_vector_type(4)));
typedef unsigned int u32x2 __attribute__((ext_vector_type(2)));

static constexpr int HM = 128, WM = 128;   // logical H,W
static constexpr int HP = 130, WP = 130;   // padded H,W

DEV unsigned short f2bf(float f) {
  unsigned int u = __float_as_uint(f);
  return (unsigned short)((u + 0x7fffu + ((u >> 16) & 1u)) >> 16);  // RNE
}
DEV float bf2f(unsigned short s) { return __uint_as_float(((unsigned int)s) << 16); }

// ---------------- scatter: points -> padded channels-last grid + occ masks ----------------
__global__ __launch_bounds__(256)
void scatter_k(const float* __restrict__ vf, const int* __restrict__ co,
               unsigned short* __restrict__ x,
               unsigned char* __restrict__ o0, unsigned char* __restrict__ o1,
               unsigned char* __restrict__ o2, unsigned char* __restrict__ o3,
               int npts) {
  int i = blockIdx.x * 256 + threadIdx.x;
  if (i >= npts) return;
  int d = co[i * 4 + 1], h = co[i * 4 + 2], w = co[i * 4 + 3];
  unsigned short* dst = x + (size_t)(((d + 1) * HP + (h + 1)) * WP + (w + 1)) * 16;
#pragma unroll
  for (int c = 0; c < 16; ++c) dst[c] = f2bf(vf[i * 16 + c]);
  int hw = h * WM + w;
  o0[d * (HM * WM) + hw] = 1;
  o1[(d >> 1) * (HM * WM) + hw] = 1;
  o2[(d >> 2) * (HM * WM) + hw] = 1;
  o3[(d >> 3) * (HM * WM) + hw] = 1;
}

// ---------------- weight repack: f32 [co][ci][27] -> bf16 [tap][co][ci] ----------------
__global__ __launch_bounds__(256)
void wcvt_k(const float* __restrict__ src, unsigned short* __restrict__ dst, int CIc, int COc) {
  int i = blockIdx.x * 256 + threadIdx.x;
  int tot = 27 * COc * CIc;
  if (i >= tot) return;
  int ci = i % CIc;
  int t = i / CIc;
  int cco = t % COc;
  int tap = t / COc;
  dst[i] = f2bf(src[(cco * CIc + ci) * 27 + tap]);
}

// ---------------- conv 3x3x3 implicit-GEMM, MFMA bf16, masked relu ----------------
// in/out: [D+2][130][130][C] bf16 zero-halo padded. Block = one padded row; interior blocks
// compute 128 voxels x CO; halo blocks just zero their output row.
template <int CI, int CO, int CIPAD>
__global__ __launch_bounds__(256)
void conv_k(const unsigned short* __restrict__ xin, unsigned short* __restrict__ xout,
            const unsigned short* __restrict__ wt, const unsigned char* __restrict__ occ,
            int D) {
  constexpr int CIS = CIPAD + 8;   // odd-16B stride: b128 frag reads spread all 32 banks
  constexpr int NM = CO / 16;      // m-fragments
  constexpr int CIB = CIPAD / 32;  // K blocks of 32
  __shared__ __align__(16) unsigned short xrow[WP * CIS];
  __shared__ __align__(16) unsigned short wl[3 * CO * CIS];

  int tid = threadIdx.x;
  int row = blockIdx.x;
  int bh = row % HP, bd = row / HP;
  int outRow = (bd * HP + bh) * WP * CO;
  if (bd == 0 || bd == D + 1 || bh == 0 || bh == HP - 1) {
    for (int i = tid; i < WP * CO; i += 256) xout[outRow + i] = 0;
    return;
  }
  int d = bd - 1, h = bh - 1;
  int wv = tid >> 6, lane = tid & 63;
  int ln = lane & 15, lg = lane >> 4;

  f32x4 acc[NM][2];
#pragma unroll
  for (int m = 0; m < NM; ++m)
#pragma unroll
    for (int j = 0; j < 2; ++j) acc[m][j] = (f32x4)0.0f;

  for (int kd = 0; kd < 3; ++kd) {
    for (int kh = 0; kh < 3; ++kh) {
      __syncthreads();
      {  // stage input row (d+kd, h+kh): [130][CI] -> xrow[130][CIS]
        const unsigned short* src = xin + (size_t)((d + kd) * HP + (h + kh)) * WP * CI;
        constexpr int CH = CI / 8;
        for (int c = tid; c < WP * CH; c += 256) {
          int w = c / CH, p = c - w * CH;
          *(u32x4*)&xrow[w * CIS + p * 8] = *(const u32x4*)(src + w * CI + p * 8);
        }
        if constexpr (CIPAD > CI) {
          constexpr int ZH = (CIPAD - CI) / 8;
          for (int c = tid; c < WP * ZH; c += 256) {
            int w = c / ZH, p = c - w * ZH;
            *(u32x4*)&xrow[w * CIS + CI + p * 8] = (u32x4)0u;
          }
        }
      }
      {  // stage 3 kw taps of weights: [3*CO][CI] -> wl[3*CO][CIS]
        int t0 = (kd * 3 + kh) * 3;
        const unsigned short* src = wt + t0 * CO * CI;
        constexpr int CH = CI / 8;
        for (int c = tid; c < 3 * CO * CH; c += 256) {
          int r = c / CH, p = c - r * CH;
          *(u32x4*)&wl[r * CIS + p * 8] = *(const u32x4*)(src + r * CI + p * 8);
        }
        if constexpr (CIPAD > CI) {
          constexpr int ZH = (CIPAD - CI) / 8;
          for (int c = tid; c < 3 * CO * ZH; c += 256) {
            int r = c / ZH, p = c - r * ZH;
            *(u32x4*)&wl[r * CIS + CI + p * 8] = (u32x4)0u;
          }
        }
      }
      __syncthreads();
#pragma unroll
      for (int kw = 0; kw < 3; ++kw) {
#pragma unroll
        for (int cb = 0; cb < CIB; ++cb) {
          int k0 = cb * 32 + lg * 8;
          s16x8 a[NM], b[2];
#pragma unroll
          for (int m = 0; m < NM; ++m)
            a[m] = *(const s16x8*)&wl[(kw * CO + m * 16 + ln) * CIS + k0];
#pragma unroll
          for (int j = 0; j < 2; ++j)
            b[j] = *(const s16x8*)&xrow[(wv * 32 + j * 16 + ln + kw) * CIS + k0];
#pragma unroll
          for (int m = 0; m < NM; ++m)
#pragma unroll
            for (int j = 0; j < 2; ++j)
              acc[m][j] = __builtin_amdgcn_mfma_f32_16x16x32_bf16(a[m], b[j], acc[m][j], 0, 0, 0);
        }
      }
    }
  }

  // epilogue: masked relu -> bf16. D-frag: col(n)=lane&15 -> voxel, row(m)=lg*4+r -> co (m89-verified)
  int occBase = (d * HM + h) * WM;
#pragma unroll
  for (int j = 0; j < 2; ++j) {
    int vox = wv * 32 + j * 16 + ln;
    float on = occ[occBase + vox] ? 1.0f : 0.0f;
    unsigned short* dst = xout + outRow + (vox + 1) * CO;
#pragma unroll
    for (int m = 0; m < NM; ++m) {
      unsigned short q0 = f2bf(fmaxf(acc[m][j][0], 0.0f) * on);
      unsigned short q1 = f2bf(fmaxf(acc[m][j][1], 0.0f) * on);
      unsigned short q2 = f2bf(fmaxf(acc[m][j][2], 0.0f) * on);
      unsigned short q3 = f2bf(fmaxf(acc[m][j][3], 0.0f) * on);
      u32x2 pv;
      pv.x = (unsigned int)q0 | ((unsigned int)q1 << 16);
      pv.y = (unsigned int)q2 | ((unsigned int)q3 << 16);
      *(u32x2*)&dst[m * 16 + lg * 4] = pv;
    }
  }
  // zero the w-halo of this output row
  for (int i = tid; i < 2 * CO; i += 256) {
    int s = i / CO, c = i - (i / CO) * CO;
    xout[outRow + (s ? (WP - 1) * CO : 0) + c] = 0;
  }
}

// ---------------- spatial 3x3x3 maxpool, stride (2,1,1), occ-masked ----------------
template <int C>
__global__ __launch_bounds__(256)
void pool_sp_k(const unsigned short* __restrict__ xin, unsigned short* __restrict__ xout,
               const unsigned char* __restrict__ oc, int Dout) {
  int row = blockIdx.x;
  int bh = row % HP, bdo = row / HP;
  int outRow = (bdo * HP + bh) * WP * C;
  int tid = threadIdx.x;
  if (bdo == 0 || bdo == Dout + 1 || bh == 0 || bh == HP - 1) {
    for (int i = tid; i < WP * C; i += 256) xout[outRow + i] = 0;
    return;
  }
  int dp = bdo - 1, h = bh - 1;
  int w = tid & 127, cg = tid >> 7;
  bool on = oc[(dp * HM + h) * WM + w] != 0;
#pragma unroll
  for (int ch = 0; ch < C / 16; ++ch) {
    int c0 = cg * (C / 2) + ch * 8;
    float mx[8];
#pragma unroll
    for (int q = 0; q < 8; ++q) mx[q] = 0.0f;
    for (int dd = 0; dd < 3; ++dd)
      for (int hh = 0; hh < 3; ++hh)
#pragma unroll
        for (int ww = 0; ww < 3; ++ww) {
          const unsigned short* p =
              xin + (size_t)(((2 * dp + dd) * HP + (bh - 1 + hh)) * WP + (w + ww)) * C + c0;
          u32x4 v = *(const u32x4*)p;
          const unsigned short* u = (const unsigned short*)&v;
#pragma unroll
          for (int q = 0; q < 8; ++q) mx[q] = fmaxf(mx[q], bf2f(u[q]));
        }
    unsigned short o[8];
#pragma unroll
    for (int q = 0; q < 8; ++q) o[q] = on ? f2bf(mx[q]) : (unsigned short)0;
    *(u32x4*)(xout + outRow + (w + 1) * C + c0) = *(const u32x4*)o;
  }
  for (int i = tid; i < 2 * C; i += 256) {
    int s = i / C, c = i - (i / C) * C;
    xout[outRow + (s ? (WP - 1) * C : 0) + c] = 0;
  }
}

// ---------------- depth-only window-3 stride-2 pool + reshape -> d_out (FLOAT32) ----------------
__global__ __launch_bounds__(256)
void pool_d_k(const unsigned short* __restrict__ xin, float* __restrict__ out,
              const unsigned char* __restrict__ oc) {
  int t = blockIdx.x * 256 + threadIdx.x;
  int w = t & 127, h = (t >> 7) & 127, dp = (t >> 14) & 1, c = t >> 15;
  if (c >= 64) return;
  float mx = 0.0f;
#pragma unroll
  for (int dd = 0; dd < 3; ++dd)
    mx = fmaxf(mx, bf2f(xin[(size_t)(((2 * dp + dd) * HP + (h + 1)) * WP + (w + 1)) * 64 + c]));
  bool on = oc[(dp * HM + h) * WM + w] != 0;
  out[((c * 2 + dp) * HM + h) * WM + w] = on ? mx : 0.0f;
}

extern "C" void kernel_launch(void* const* d_in, const int* in_sizes, int n_in,
                              void* d_out, int out_size, void* d_ws, size_t ws_size,
                              hipStream_t stream) {
  (void)n_in; (void)out_size; (void)ws_size;
  const float* vf = (const float*)d_in[0];
  const int* co = (const int*)d_in[1];
  const float* wsrc[8] = {(const float*)d_in[3], (const float*)d_in[4], (const float*)d_in[5],
                          (const float*)d_in[6], (const float*)d_in[7], (const float*)d_in[8],
                          (const float*)d_in[9], (const float*)d_in[10]};
  int npts = in_sizes[1] / 4;

  char* ws = (char*)d_ws;
  const size_t SA = (size_t)18 * 130 * 130 * 64 * 2;  // 38,937,600 B (max A-buffer extent)
  const size_t SB = (size_t)10 * 130 * 130 * 64 * 2;  // 21,632,000 B (max B-buffer extent)
  unsigned short* xA = (unsigned short*)ws;
  unsigned short* xB = (unsigned short*)(ws + SA);
  unsigned char* occ0 = (unsigned char*)(ws + SA + SB);
  unsigned char* occ1 = occ0 + 16 * HM * WM;
  unsigned char* occ2 = occ1 + 8 * HM * WM;
  unsigned char* occ3 = occ2 + 4 * HM * WM;
  unsigned short* wb[8];
  {
    unsigned short* p = (unsigned short*)(occ3 + 2 * HM * WM);
    const int wsz[8] = {27 * 32 * 16, 27 * 64 * 32, 27 * 64 * 64, 27 * 64 * 64,
                        27 * 64 * 64, 27 * 64 * 64, 27 * 64 * 64, 27 * 64 * 64};
    for (int i = 0; i < 8; ++i) { wb[i] = p; p += wsz[i]; }
  }

  // scatter background (C=16 extent of xA) + occ masks must be zero each call
  hipMemsetAsync(xA, 0, (size_t)18 * 130 * 130 * 16 * 2, stream);
  hipMemsetAsync(occ0, 0, (size_t)(16 + 8 + 4 + 2) * HM * WM, stream);

  scatter_k<<<(npts + 255) / 256, 256, 0, stream>>>(vf, co, xA, occ0, occ1, occ2, occ3, npts);

  const int cis[8] = {16, 32, 64, 64, 64, 64, 64, 64};
  const int cos_[8] = {32, 64, 64, 64, 64, 64, 64, 64};
  for (int i = 0; i < 8; ++i) {
    int tot = 27 * cos_[i] * cis[i];
    wcvt_k<<<(tot + 255) / 256, 256, 0, stream>>>(wsrc[i], wb[i], cis[i], cos_[i]);
  }

  conv_k<16, 32, 32><<<18 * HP, 256, 0, stream>>>(xA, xB, wb[0], occ0, 16);  // xB: [18][..][32]
  conv_k<32, 64, 32><<<18 * HP, 256, 0, stream>>>(xB, xA, wb[1], occ0, 16);  // xA: [18][..][64]
  pool_sp_k<64><<<10 * HP, 256, 0, stream>>>(xA, xB, occ1, 8);               // xB: [10][..][64]
  conv_k<64, 64, 64><<<10 * HP, 256, 0, stream>>>(xB, xA, wb[2], occ1, 8);
  conv_k<64, 64, 64><<<10 * HP, 256, 0, stream>>>(xA, xB, wb[3], occ1, 8);
  conv_k<64, 64, 64><<<10 * HP, 256, 0, stream>>>(xB, xA, wb[4], occ1, 8);
  pool_sp_k<64><<<6 * HP, 256, 0, stream>>>(xA, xB, occ2, 4);                // xB: [6][..][64]
  conv_k<64, 64, 64><<<6 * HP, 256, 0, stream>>>(xB, xA, wb[5], occ2, 4);
  conv_k<64, 64, 64><<<6 * HP, 256, 0, stream>>>(xA, xB, wb[6], occ2, 4);
  conv_k<64, 64, 64><<<6 * HP, 256, 0, stream>>>(xB, xA, wb[7], occ2, 4);
  pool_d_k<<<(64 * 2 * HM * WM) / 256, 256, 0, stream>>>(xA, (float*)d_out, occ3);
}

// Round 3
// 505.466 us; speedup vs baseline: 1.3610x; 1.3610x over previous
//
#include <hip/hip_runtime.h>
#include <stdint.h>

#define DEV __device__ __forceinline__

typedef float f32x4 __attribute__((ext_vector_type(4)));
typedef short s16x8 __attribute__((ext_vector_type(8)));
typedef unsigned int u32x4 __attribute__((ext_vector_type(4)));
typedef unsigned int u32x2 __attribute__((ext_vector_type(2)));

static constexpr int HM = 128, WM = 128;   // logical H,W
static constexpr int HP = 130, WP = 130;   // padded H,W

DEV unsigned short f2bf(float f) {
  unsigned int u = __float_as_uint(f);
  return (unsigned short)((u + 0x7fffu + ((u >> 16) & 1u)) >> 16);  // RNE
}
DEV float bf2f(unsigned short s) { return __uint_as_float(((unsigned int)s) << 16); }

// ---------------- scatter: points -> padded channels-last grid + occ masks ----------------
__global__ __launch_bounds__(256)
void scatter_k(const float* __restrict__ vf, const int* __restrict__ co,
               unsigned short* __restrict__ x,
               unsigned char* __restrict__ o0, unsigned char* __restrict__ o1,
               unsigned char* __restrict__ o2, unsigned char* __restrict__ o3,
               int npts) {
  int i = blockIdx.x * 256 + threadIdx.x;
  if (i >= npts) return;
  int d = co[i * 4 + 1], h = co[i * 4 + 2], w = co[i * 4 + 3];
  unsigned short* dst = x + (size_t)(((d + 1) * HP + (h + 1)) * WP + (w + 1)) * 16;
#pragma unroll
  for (int c = 0; c < 16; ++c) dst[c] = f2bf(vf[i * 16 + c]);
  int hw = h * WM + w;
  o0[d * (HM * WM) + hw] = 1;
  o1[(d >> 1) * (HM * WM) + hw] = 1;
  o2[(d >> 2) * (HM * WM) + hw] = 1;
  o3[(d >> 3) * (HM * WM) + hw] = 1;
}

// ---------------- weight repack: f32 [co][ci][27] -> bf16 [tap][co][ci] ----------------
__global__ __launch_bounds__(256)
void wcvt_k(const float* __restrict__ src, unsigned short* __restrict__ dst, int CIc, int COc) {
  int i = blockIdx.x * 256 + threadIdx.x;
  int tot = 27 * COc * CIc;
  if (i >= tot) return;
  int ci = i % CIc;
  int t = i / CIc;
  int cco = t % COc;
  int tap = t / COc;
  dst[i] = f2bf(src[(cco * CIc + ci) * 27 + tap]);
}

// ---------------- conv 3x3x3 implicit-GEMM, MFMA bf16, masked relu ----------------
template <int CI, int CO, int CIPAD>
__global__ __launch_bounds__(256)
void conv_k(const unsigned short* __restrict__ xin, unsigned short* __restrict__ xout,
            const unsigned short* __restrict__ wt, const unsigned char* __restrict__ occ,
            int D) {
  constexpr int CIS = CIPAD + 8;   // odd-16B stride: b128 frag reads spread all 32 banks
  constexpr int NM = CO / 16;      // m-fragments
  constexpr int CIB = CIPAD / 32;  // K blocks of 32
  __shared__ __align__(16) unsigned short xrow[WP * CIS];
  __shared__ __align__(16) unsigned short wl[3 * CO * CIS];

  int tid = threadIdx.x;
  int row = blockIdx.x;
  int bh = row % HP, bd = row / HP;
  int outRow = (bd * HP + bh) * WP * CO;
  if (bd == 0 || bd == D + 1 || bh == 0 || bh == HP - 1) {
    for (int i = tid; i < WP * CO; i += 256) xout[outRow + i] = 0;
    return;
  }
  int d = bd - 1, h = bh - 1;
  int wv = tid >> 6, lane = tid & 63;
  int ln = lane & 15, lg = lane >> 4;

  f32x4 acc[NM][2];
#pragma unroll
  for (int m = 0; m < NM; ++m)
#pragma unroll
    for (int j = 0; j < 2; ++j) acc[m][j] = (f32x4)0.0f;

  for (int kd = 0; kd < 3; ++kd) {
    for (int kh = 0; kh < 3; ++kh) {
      __syncthreads();
      {  // stage input row (d+kd, h+kh): [130][CI] -> xrow[130][CIS]
        const unsigned short* src = xin + (size_t)((d + kd) * HP + (h + kh)) * WP * CI;
        constexpr int CH = CI / 8;
        for (int c = tid; c < WP * CH; c += 256) {
          int w = c / CH, p = c - w * CH;
          *(u32x4*)&xrow[w * CIS + p * 8] = *(const u32x4*)(src + w * CI + p * 8);
        }
        if constexpr (CIPAD > CI) {
          constexpr int ZH = (CIPAD - CI) / 8;
          for (int c = tid; c < WP * ZH; c += 256) {
            int w = c / ZH, p = c - w * ZH;
            *(u32x4*)&xrow[w * CIS + CI + p * 8] = (u32x4)0u;
          }
        }
      }
      {  // stage 3 kw taps of weights: [3*CO][CI] -> wl[3*CO][CIS]
        int t0 = (kd * 3 + kh) * 3;
        const unsigned short* src = wt + t0 * CO * CI;
        constexpr int CH = CI / 8;
        for (int c = tid; c < 3 * CO * CH; c += 256) {
          int r = c / CH, p = c - r * CH;
          *(u32x4*)&wl[r * CIS + p * 8] = *(const u32x4*)(src + r * CI + p * 8);
        }
        if constexpr (CIPAD > CI) {
          constexpr int ZH = (CIPAD - CI) / 8;
          for (int c = tid; c < 3 * CO * ZH; c += 256) {
            int r = c / ZH, p = c - r * ZH;
            *(u32x4*)&wl[r * CIS + CI + p * 8] = (u32x4)0u;
          }
        }
      }
      __syncthreads();
#pragma unroll
      for (int kw = 0; kw < 3; ++kw) {
#pragma unroll
        for (int cb = 0; cb < CIB; ++cb) {
          int k0 = cb * 32 + lg * 8;
          s16x8 a[NM], b[2];
#pragma unroll
          for (int m = 0; m < NM; ++m)
            a[m] = *(const s16x8*)&wl[(kw * CO + m * 16 + ln) * CIS + k0];
#pragma unroll
          for (int j = 0; j < 2; ++j)
            b[j] = *(const s16x8*)&xrow[(wv * 32 + j * 16 + ln + kw) * CIS + k0];
#pragma unroll
          for (int m = 0; m < NM; ++m)
#pragma unroll
            for (int j = 0; j < 2; ++j)
              acc[m][j] = __builtin_amdgcn_mfma_f32_16x16x32_bf16(a[m], b[j], acc[m][j], 0, 0, 0);
        }
      }
    }
  }

  // epilogue: masked relu -> bf16. D-frag: col(n)=lane&15 -> voxel, row(m)=lg*4+r -> co
  int occBase = (d * HM + h) * WM;
#pragma unroll
  for (int j = 0; j < 2; ++j) {
    int vox = wv * 32 + j * 16 + ln;
    float on = occ[occBase + vox] ? 1.0f : 0.0f;
    unsigned short* dst = xout + outRow + (vox + 1) * CO;
#pragma unroll
    for (int m = 0; m < NM; ++m) {
      unsigned short q0 = f2bf(fmaxf(acc[m][j][0], 0.0f) * on);
      unsigned short q1 = f2bf(fmaxf(acc[m][j][1], 0.0f) * on);
      unsigned short q2 = f2bf(fmaxf(acc[m][j][2], 0.0f) * on);
      unsigned short q3 = f2bf(fmaxf(acc[m][j][3], 0.0f) * on);
      u32x2 pv;
      pv.x = (unsigned int)q0 | ((unsigned int)q1 << 16);
      pv.y = (unsigned int)q2 | ((unsigned int)q3 << 16);
      *(u32x2*)&dst[m * 16 + lg * 4] = pv;
    }
  }
  // zero the w-halo of this output row
  for (int i = tid; i < 2 * CO; i += 256) {
    int s = i / CO, c = i - (i / CO) * CO;
    xout[outRow + (s ? (WP - 1) * CO : 0) + c] = 0;
  }
}

// ---------------- spatial 3x3x3 maxpool, stride (2,1,1), occ-masked ----------------
// Separable: phase 1 = vertical (9 rows) max -> LDS, phase 2 = 3-tap horizontal max.
// Thread map (w, c8) with c8 fast -> 8 lanes cover one voxel's contiguous 128B (coalesced).
template <int C>
__global__ __launch_bounds__(256)
void pool_sp_k(const unsigned short* __restrict__ xin, unsigned short* __restrict__ xout,
               const unsigned char* __restrict__ oc, int Dout) {
  constexpr int CH = C / 8;
  __shared__ __align__(16) unsigned short vm[WP * C];  // 130*64*2B = 16.6 KB
  int row = blockIdx.x;
  int bh = row % HP, bdo = row / HP;
  int outRow = (bdo * HP + bh) * WP * C;
  int tid = threadIdx.x;
  if (bdo == 0 || bdo == Dout + 1 || bh == 0 || bh == HP - 1) {
    for (int i = tid; i < WP * C; i += 256) xout[outRow + i] = 0;
    return;
  }
  int dp = bdo - 1, h = bh - 1;

  // phase 1: vm[w][c] = max over 9 (dd,hh) input rows (padded indices, halos are zero)
  for (int idx = tid; idx < WP * CH; idx += 256) {
    int w = idx / CH, c8 = idx - w * CH;
    float mx[8];
#pragma unroll
    for (int q = 0; q < 8; ++q) mx[q] = 0.0f;
#pragma unroll
    for (int dd = 0; dd < 3; ++dd)
#pragma unroll
      for (int hh = 0; hh < 3; ++hh) {
        const unsigned short* p =
            xin + ((size_t)((2 * dp + dd) * HP + (h + hh)) * WP + w) * C + c8 * 8;
        u32x4 v = *(const u32x4*)p;
        const unsigned short* u = (const unsigned short*)&v;
#pragma unroll
        for (int q = 0; q < 8; ++q) mx[q] = fmaxf(mx[q], bf2f(u[q]));
      }
    unsigned short o[8];
#pragma unroll
    for (int q = 0; q < 8; ++q) o[q] = f2bf(mx[q]);  // exact: max of bf16 values
    *(u32x4*)&vm[w * C + c8 * 8] = *(const u32x4*)o;
  }
  __syncthreads();

  // phase 2: horizontal 3-tap max + occ mask + coalesced store
  for (int idx = tid; idx < WM * CH; idx += 256) {
    int w = idx / CH, c8 = idx - w * CH;  // w = logical 0..127
    float mx[8];
#pragma unroll
    for (int q = 0; q < 8; ++q) mx[q] = 0.0f;
#pragma unroll
    for (int ww = 0; ww < 3; ++ww) {
      u32x4 v = *(const u32x4*)&vm[(w + ww) * C + c8 * 8];
      const unsigned short* u = (const unsigned short*)&v;
#pragma unroll
      for (int q = 0; q < 8; ++q) mx[q] = fmaxf(mx[q], bf2f(u[q]));
    }
    bool on = oc[(dp * HM + h) * WM + w] != 0;
    unsigned short o[8];
#pragma unroll
    for (int q = 0; q < 8; ++q) o[q] = on ? f2bf(mx[q]) : (unsigned short)0;
    *(u32x4*)(xout + outRow + (w + 1) * C + c8 * 8) = *(const u32x4*)o;
  }
  // zero the w-halo of this output row
  for (int i = tid; i < 2 * C; i += 256) {
    int s = i / C, c = i - (i / C) * C;
    xout[outRow + (s ? (WP - 1) * C : 0) + c] = 0;
  }
}

// ---------------- depth-only window-3 stride-2 pool + reshape -> d_out (FLOAT32) ----------------
// Thread map: c8 fast (coalesced reads). Writes are strided by channel but total write
// traffic is only 8.4 MB -> L2 write-combining absorbs it.
__global__ __launch_bounds__(256)
void pool_d_k(const unsigned short* __restrict__ xin, float* __restrict__ out,
              const unsigned char* __restrict__ oc) {
  int t = blockIdx.x * 256 + threadIdx.x;  // 2*128*128*8 = 262144 threads
  int c8 = t & 7, w = (t >> 3) & 127, h = (t >> 10) & 127, dp = (t >> 17) & 1;
  float mx[8];
#pragma unroll
  for (int q = 0; q < 8; ++q) mx[q] = 0.0f;
#pragma unroll
  for (int dd = 0; dd < 3; ++dd) {
    const unsigned short* p =
        xin + ((size_t)((2 * dp + dd) * HP + (h + 1)) * WP + (w + 1)) * 64 + c8 * 8;
    u32x4 v = *(const u32x4*)p;
    const unsigned short* u = (const unsigned short*)&v;
#pragma unroll
    for (int q = 0; q < 8; ++q) mx[q] = fmaxf(mx[q], bf2f(u[q]));
  }
  bool on = oc[(dp * HM + h) * WM + w] != 0;
#pragma unroll
  for (int q = 0; q < 8; ++q) {
    int c = c8 * 8 + q;
    out[((c * 2 + dp) * HM + h) * WM + w] = on ? mx[q] : 0.0f;
  }
}

extern "C" void kernel_launch(void* const* d_in, const int* in_sizes, int n_in,
                              void* d_out, int out_size, void* d_ws, size_t ws_size,
                              hipStream_t stream) {
  (void)n_in; (void)out_size; (void)ws_size;
  const float* vf = (const float*)d_in[0];
  const int* co = (const int*)d_in[1];
  const float* wsrc[8] = {(const float*)d_in[3], (const float*)d_in[4], (const float*)d_in[5],
                          (const float*)d_in[6], (const float*)d_in[7], (const float*)d_in[8],
                          (const float*)d_in[9], (const float*)d_in[10]};
  int npts = in_sizes[1] / 4;

  char* ws = (char*)d_ws;
  const size_t SA = (size_t)18 * 130 * 130 * 64 * 2;  // max A-buffer extent
  const size_t SB = (size_t)10 * 130 * 130 * 64 * 2;  // max B-buffer extent
  unsigned short* xA = (unsigned short*)ws;
  unsigned short* xB = (unsigned short*)(ws + SA);
  unsigned char* occ0 = (unsigned char*)(ws + SA + SB);
  unsigned char* occ1 = occ0 + 16 * HM * WM;
  unsigned char* occ2 = occ1 + 8 * HM * WM;
  unsigned char* occ3 = occ2 + 4 * HM * WM;
  unsigned short* wb[8];
  {
    unsigned short* p = (unsigned short*)(occ3 + 2 * HM * WM);
    const int wsz[8] = {27 * 32 * 16, 27 * 64 * 32, 27 * 64 * 64, 27 * 64 * 64,
                        27 * 64 * 64, 27 * 64 * 64, 27 * 64 * 64, 27 * 64 * 64};
    for (int i = 0; i < 8; ++i) { wb[i] = p; p += wsz[i]; }
  }

  // scatter background (C=16 extent of xA) + occ masks must be zero each call
  hipMemsetAsync(xA, 0, (size_t)18 * 130 * 130 * 16 * 2, stream);
  hipMemsetAsync(occ0, 0, (size_t)(16 + 8 + 4 + 2) * HM * WM, stream);

  scatter_k<<<(npts + 255) / 256, 256, 0, stream>>>(vf, co, xA, occ0, occ1, occ2, occ3, npts);

  const int cis[8] = {16, 32, 64, 64, 64, 64, 64, 64};
  const int cos_[8] = {32, 64, 64, 64, 64, 64, 64, 64};
  for (int i = 0; i < 8; ++i) {
    int tot = 27 * cos_[i] * cis[i];
    wcvt_k<<<(tot + 255) / 256, 256, 0, stream>>>(wsrc[i], wb[i], cis[i], cos_[i]);
  }

  conv_k<16, 32, 32><<<18 * HP, 256, 0, stream>>>(xA, xB, wb[0], occ0, 16);  // xB: [18][..][32]
  conv_k<32, 64, 32><<<18 * HP, 256, 0, stream>>>(xB, xA, wb[1], occ0, 16);  // xA: [18][..][64]
  pool_sp_k<64><<<10 * HP, 256, 0, stream>>>(xA, xB, occ1, 8);               // xB: [10][..][64]
  conv_k<64, 64, 64><<<10 * HP, 256, 0, stream>>>(xB, xA, wb[2], occ1, 8);
  conv_k<64, 64, 64><<<10 * HP, 256, 0, stream>>>(xA, xB, wb[3], occ1, 8);
  conv_k<64, 64, 64><<<10 * HP, 256, 0, stream>>>(xB, xA, wb[4], occ1, 8);
  pool_sp_k<64><<<6 * HP, 256, 0, stream>>>(xA, xB, occ2, 4);                // xB: [6][..][64]
  conv_k<64, 64, 64><<<6 * HP, 256, 0, stream>>>(xB, xA, wb[5], occ2, 4);
  conv_k<64, 64, 64><<<6 * HP, 256, 0, stream>>>(xA, xB, wb[6], occ2, 4);
  conv_k<64, 64, 64><<<6 * HP, 256, 0, stream>>>(xB, xA, wb[7], occ2, 4);
  pool_d_k<<<(2 * 128 * 128 * 8) / 256, 256, 0, stream>>>(xA, (float*)d_out, occ3);
}

// Round 4
// 378.732 us; speedup vs baseline: 1.8164x; 1.3346x over previous
//
#include <hip/hip_runtime.h>
#include <stdint.h>

#define DEV __device__ __forceinline__

typedef float f32x4 __attribute__((ext_vector_type(4)));
typedef short s16x8 __attribute__((ext_vector_type(8)));
typedef unsigned int u32x4 __attribute__((ext_vector_type(4)));
typedef unsigned int u32x2 __attribute__((ext_vector_type(2)));

static constexpr int HM = 128, WM = 128;   // logical H,W
static constexpr int HP = 130, WP = 130;   // padded H,W

DEV unsigned short f2bf(float f) {
  unsigned int u = __float_as_uint(f);
  return (unsigned short)((u + 0x7fffu + ((u >> 16) & 1u)) >> 16);  // RNE
}
DEV float bf2f(unsigned short s) { return __uint_as_float(((unsigned int)s) << 16); }

// ---------------- scatter: points -> padded channels-last grid + occ masks ----------------
__global__ __launch_bounds__(256)
void scatter_k(const float* __restrict__ vf, const int* __restrict__ co,
               unsigned short* __restrict__ x,
               unsigned char* __restrict__ o0, unsigned char* __restrict__ o1,
               unsigned char* __restrict__ o2, unsigned char* __restrict__ o3,
               int npts) {
  int i = blockIdx.x * 256 + threadIdx.x;
  if (i >= npts) return;
  int d = co[i * 4 + 1], h = co[i * 4 + 2], w = co[i * 4 + 3];
  unsigned short* dst = x + (size_t)(((d + 1) * HP + (h + 1)) * WP + (w + 1)) * 16;
#pragma unroll
  for (int c = 0; c < 16; ++c) dst[c] = f2bf(vf[i * 16 + c]);
  int hw = h * WM + w;
  o0[d * (HM * WM) + hw] = 1;
  o1[(d >> 1) * (HM * WM) + hw] = 1;
  o2[(d >> 2) * (HM * WM) + hw] = 1;
  o3[(d >> 3) * (HM * WM) + hw] = 1;
}

// ---------------- fused weight repack: f32 [co][ci][27] -> bf16 [tap][co][ci], all 8 ----------------
__global__ __launch_bounds__(256)
void wcvt_all_k(const float* s0, const float* s1, const float* s2, const float* s3,
                const float* s4, const float* s5, const float* s6, const float* s7,
                unsigned short* __restrict__ dst) {
  int t = blockIdx.x * 256 + threadIdx.x;
  const int CIa[8] = {16, 32, 64, 64, 64, 64, 64, 64};
  const int COa[8] = {32, 64, 64, 64, 64, 64, 64, 64};
  const float* srcs[8] = {s0, s1, s2, s3, s4, s5, s6, s7};
  int start = 0;
#pragma unroll
  for (int i = 0; i < 8; ++i) {
    int sz = 27 * COa[i] * CIa[i];
    if (t >= start && t < start + sz) {
      int l = t - start;
      int ci = l % CIa[i];
      int r = l / CIa[i];
      int cco = r % COa[i];
      int tap = r / COa[i];
      dst[t] = f2bf(srcs[i][(cco * CIa[i] + ci) * 27 + tap]);
    }
    start += sz;
  }
}

// ---------------- conv 3x3x3 implicit-GEMM, MFMA bf16, masked relu ----------------
// Block = 2 output rows x 128 vox x CO (256 thr, 4 waves x 64 vox). Per (kd,kh) stage:
// ds_write prev-issued regs -> issue next-stage global loads (T14 split) -> barrier -> MFMA.
// LDS XOR-swizzled (slot ^= v&(SLOTS-1)) on both write & read -> conflict-free b128.
// Last 64 blocks of the grid zero the output halo surface (planes 0/D+1, rows/cols 0/129).
template <int CI, int CO, int CIPAD>
__global__ __launch_bounds__(256, 2)
void conv_k(const unsigned short* __restrict__ xin, unsigned short* __restrict__ xout,
            const unsigned short* __restrict__ wt, const unsigned char* __restrict__ occ,
            int D) {
  constexpr int SLOTS = CIPAD / 8;   // 16B slots per voxel channel-vector
  constexpr int CIB = CIPAD / 32;    // K blocks of 32
  constexpr int NM = CO / 16;        // m-fragments
  constexpr int NCX = 2 * 130 * SLOTS;
  constexpr int NCW = 3 * CO * SLOTS;
  constexpr int KX = (NCX + 255) / 256;
  constexpr int KW = (NCW + 255) / 256;
  __shared__ __align__(16) unsigned short xs[2 * 130 * CIPAD];
  __shared__ __align__(16) unsigned short wls[3 * CO * CIPAD];

  int nb = gridDim.x;  // always divisible by 8
  int bid = blockIdx.x;
  int blk = (bid & 7) * (nb >> 3) + (bid >> 3);  // XCD-chunked swizzle (bijective: nb%8==0)
  int tid = threadIdx.x;
  int nint = D * 64;
  if (blk >= nint) {  // ---- halo-zero blocks ----
    constexpr int CH8 = CO / 8;
    int k = blk - nint;
    int hv = 2 * HP * WP + D * (2 * WP + 2 * HM);
    for (int c = k * 256 + tid; c < hv * CH8; c += 64 * 256) {
      int i = c / CH8, sub = c - (c / CH8) * CH8;
      int p, hh, ww;
      if (i < 2 * HP * WP) {
        p = (i >= HP * WP) ? (D + 1) : 0;
        int rem = i - ((i >= HP * WP) ? HP * WP : 0);
        hh = rem / WP; ww = rem - hh * WP;
      } else {
        constexpr int PH = 2 * WP + 2 * HM;
        int j2 = i - 2 * HP * WP;
        p = j2 / PH + 1;
        int r2 = j2 - (p - 1) * PH;
        if (r2 < 2 * WP) { hh = (r2 >= WP) ? (HP - 1) : 0; ww = r2 % WP; }
        else { int r3 = r2 - 2 * WP; hh = 1 + (r3 & 127); ww = (r3 < HM) ? 0 : (WP - 1); }
      }
      *(u32x4*)(xout + ((size_t)(p * HP + hh) * WP + ww) * CO + sub * 8) = (u32x4)0u;
    }
    return;
  }

  int d = blk >> 6, h0 = (blk & 63) * 2;
  int lane = tid & 63, wv = tid >> 6, ln = lane & 15, lg = lane >> 4;

  u32x4 rx[KX], rw[KW];
  auto ldst = [&](int kd, int kh) {
#pragma unroll
    for (int i2 = 0; i2 < KX; ++i2) {
      int c = tid + 256 * i2;
      if (NCX % 256 == 0 || c < NCX) {
        int v = c / SLOTS, slot = c - (c / SLOTS) * SLOTS;
        int s = v >= 130;
        int wp2 = v - s * 130;
        int hin = h0 + kh + s, pd = d + kd;
        if (slot * 16 < CI * 2)
          rx[i2] = *(const u32x4*)((const char*)xin +
                                   ((size_t)(pd * HP + hin) * WP + wp2) * (CI * 2) + slot * 16);
        else
          rx[i2] = (u32x4)0u;  // conv1: zero-pad channels 16..31
      }
    }
#pragma unroll
    for (int i2 = 0; i2 < KW; ++i2) {
      int c = tid + 256 * i2;
      if (NCW % 256 == 0 || c < NCW) {
        int u = c / SLOTS, slot = c - (c / SLOTS) * SLOTS;
        int tap = (kd * 3 + kh) * 3 + u / CO, cco = u - (u / CO) * CO;
        if (slot * 16 < CI * 2)
          rw[i2] = *(const u32x4*)((const char*)wt + ((size_t)(tap * CO + cco)) * (CI * 2) +
                                   slot * 16);
        else
          rw[i2] = (u32x4)0u;
      }
    }
  };

  f32x4 acc[NM][4];
#pragma unroll
  for (int m = 0; m < NM; ++m)
#pragma unroll
    for (int j = 0; j < 4; ++j) acc[m][j] = (f32x4)0.0f;

  ldst(0, 0);
  for (int kd = 0; kd < 3; ++kd) {
    for (int kh = 0; kh < 3; ++kh) {
      __syncthreads();  // previous stage's readers done
      // ds_write the pre-loaded stage (swizzled)
#pragma unroll
      for (int i2 = 0; i2 < KX; ++i2) {
        int c = tid + 256 * i2;
        if (NCX % 256 == 0 || c < NCX) {
          int v = c / SLOTS, slot = c - (c / SLOTS) * SLOTS;
          *(u32x4*)((char*)xs + v * (CIPAD * 2) + ((slot ^ (v & (SLOTS - 1))) * 16)) = rx[i2];
        }
      }
#pragma unroll
      for (int i2 = 0; i2 < KW; ++i2) {
        int c = tid + 256 * i2;
        if (NCW % 256 == 0 || c < NCW) {
          int u = c / SLOTS, slot = c - (c / SLOTS) * SLOTS;
          *(u32x4*)((char*)wls + u * (CIPAD * 2) + ((slot ^ (u & (SLOTS - 1))) * 16)) = rw[i2];
        }
      }
      // issue next stage's global loads (land during MFMA phase)
      int nkh = kh + 1, nkd = kd;
      if (nkh == 3) { nkh = 0; ++nkd; }
      if (nkd < 3) ldst(nkd, nkh);
      __syncthreads();  // staged data visible
      // MFMA phase
#pragma unroll
      for (int kw = 0; kw < 3; ++kw) {
#pragma unroll
        for (int cb = 0; cb < CIB; ++cb) {
          int slot = cb * 4 + lg;
          s16x8 a[NM], b[4];
#pragma unroll
          for (int m = 0; m < NM; ++m) {
            int u = kw * CO + m * 16 + ln;
            a[m] = *(const s16x8*)((const char*)wls + u * (CIPAD * 2) +
                                   ((slot ^ (u & (SLOTS - 1))) * 16));
          }
#pragma unroll
          for (int j = 0; j < 4; ++j) {
            int vox = wv * 64 + j * 16 + ln;
            int v = (vox >> 7) * 130 + (vox & 127) + kw;
            b[j] = *(const s16x8*)((const char*)xs + v * (CIPAD * 2) +
                                   ((slot ^ (v & (SLOTS - 1))) * 16));
          }
#pragma unroll
          for (int m = 0; m < NM; ++m)
#pragma unroll
            for (int j = 0; j < 4; ++j)
              acc[m][j] = __builtin_amdgcn_mfma_f32_16x16x32_bf16(a[m], b[j], acc[m][j], 0, 0, 0);
        }
      }
    }
  }

  // epilogue: masked relu -> bf16. D-frag: col(n)=lane&15 -> voxel, row(m)=lg*4+r -> co
#pragma unroll
  for (int j = 0; j < 4; ++j) {
    int vox = wv * 64 + j * 16 + ln;
    int r = vox >> 7, w2 = vox & 127;
    float on = occ[(d * HM + (h0 + r)) * WM + w2] ? 1.0f : 0.0f;
    unsigned short* dst = xout + ((size_t)((d + 1) * HP + (h0 + r + 1)) * WP + (w2 + 1)) * CO;
#pragma unroll
    for (int m = 0; m < NM; ++m) {
      unsigned short q0 = f2bf(fmaxf(acc[m][j][0], 0.0f) * on);
      unsigned short q1 = f2bf(fmaxf(acc[m][j][1], 0.0f) * on);
      unsigned short q2 = f2bf(fmaxf(acc[m][j][2], 0.0f) * on);
      unsigned short q3 = f2bf(fmaxf(acc[m][j][3], 0.0f) * on);
      u32x2 pv;
      pv.x = (unsigned int)q0 | ((unsigned int)q1 << 16);
      pv.y = (unsigned int)q2 | ((unsigned int)q3 << 16);
      *(u32x2*)&dst[m * 16 + lg * 4] = pv;
    }
  }
}

// ---------------- spatial 3x3x3 maxpool, stride (2,1,1), occ-masked ----------------
template <int C>
__global__ __launch_bounds__(256)
void pool_sp_k(const unsigned short* __restrict__ xin, unsigned short* __restrict__ xout,
               const unsigned char* __restrict__ oc, int Dout) {
  constexpr int CH = C / 8;
  __shared__ __align__(16) unsigned short vm[WP * C];
  int row = blockIdx.x;
  int bh = row % HP, bdo = row / HP;
  int outRow = (bdo * HP + bh) * WP * C;
  int tid = threadIdx.x;
  if (bdo == 0 || bdo == Dout + 1 || bh == 0 || bh == HP - 1) {
    for (int i = tid; i < WP * C; i += 256) xout[outRow + i] = 0;
    return;
  }
  int dp = bdo - 1, h = bh - 1;

  for (int idx = tid; idx < WP * CH; idx += 256) {
    int w = idx / CH, c8 = idx - w * CH;
    float mx[8];
#pragma unroll
    for (int q = 0; q < 8; ++q) mx[q] = 0.0f;
#pragma unroll
    for (int dd = 0; dd < 3; ++dd)
#pragma unroll
      for (int hh = 0; hh < 3; ++hh) {
        const unsigned short* p =
            xin + ((size_t)((2 * dp + dd) * HP + (h + hh)) * WP + w) * C + c8 * 8;
        u32x4 v = *(const u32x4*)p;
        const unsigned short* u = (const unsigned short*)&v;
#pragma unroll
        for (int q = 0; q < 8; ++q) mx[q] = fmaxf(mx[q], bf2f(u[q]));
      }
    unsigned short o[8];
#pragma unroll
    for (int q = 0; q < 8; ++q) o[q] = f2bf(mx[q]);
    *(u32x4*)&vm[w * C + c8 * 8] = *(const u32x4*)o;
  }
  __syncthreads();

  for (int idx = tid; idx < WM * CH; idx += 256) {
    int w = idx / CH, c8 = idx - w * CH;
    float mx[8];
#pragma unroll
    for (int q = 0; q < 8; ++q) mx[q] = 0.0f;
#pragma unroll
    for (int ww = 0; ww < 3; ++ww) {
      u32x4 v = *(const u32x4*)&vm[(w + ww) * C + c8 * 8];
      const unsigned short* u = (const unsigned short*)&v;
#pragma unroll
      for (int q = 0; q < 8; ++q) mx[q] = fmaxf(mx[q], bf2f(u[q]));
    }
    bool on = oc[(dp * HM + h) * WM + w] != 0;
    unsigned short o[8];
#pragma unroll
    for (int q = 0; q < 8; ++q) o[q] = on ? f2bf(mx[q]) : (unsigned short)0;
    *(u32x4*)(xout + outRow + (w + 1) * C + c8 * 8) = *(const u32x4*)o;
  }
  for (int i = tid; i < 2 * C; i += 256) {
    int s = i / C, c = i - (i / C) * C;
    xout[outRow + (s ? (WP - 1) * C : 0) + c] = 0;
  }
}

// ---------------- depth-only window-3 stride-2 pool + reshape -> d_out (FLOAT32) ----------------
__global__ __launch_bounds__(256)
void pool_d_k(const unsigned short* __restrict__ xin, float* __restrict__ out,
              const unsigned char* __restrict__ oc) {
  int t = blockIdx.x * 256 + threadIdx.x;
  int c8 = t & 7, w = (t >> 3) & 127, h = (t >> 10) & 127, dp = (t >> 17) & 1;
  float mx[8];
#pragma unroll
  for (int q = 0; q < 8; ++q) mx[q] = 0.0f;
#pragma unroll
  for (int dd = 0; dd < 3; ++dd) {
    const unsigned short* p =
        xin + ((size_t)((2 * dp + dd) * HP + (h + 1)) * WP + (w + 1)) * 64 + c8 * 8;
    u32x4 v = *(const u32x4*)p;
    const unsigned short* u = (const unsigned short*)&v;
#pragma unroll
    for (int q = 0; q < 8; ++q) mx[q] = fmaxf(mx[q], bf2f(u[q]));
  }
  bool on = oc[(dp * HM + h) * WM + w] != 0;
#pragma unroll
  for (int q = 0; q < 8; ++q) {
    int c = c8 * 8 + q;
    out[((c * 2 + dp) * HM + h) * WM + w] = on ? mx[q] : 0.0f;
  }
}

extern "C" void kernel_launch(void* const* d_in, const int* in_sizes, int n_in,
                              void* d_out, int out_size, void* d_ws, size_t ws_size,
                              hipStream_t stream) {
  (void)n_in; (void)out_size; (void)ws_size;
  const float* vf = (const float*)d_in[0];
  const int* co = (const int*)d_in[1];
  int npts = in_sizes[1] / 4;

  char* ws = (char*)d_ws;
  const size_t SA = (size_t)18 * 130 * 130 * 64 * 2;  // max A-buffer extent
  const size_t SB = (size_t)10 * 130 * 130 * 64 * 2;  // max B-buffer extent
  unsigned short* xA = (unsigned short*)ws;
  unsigned short* xB = (unsigned short*)(ws + SA);
  unsigned char* occ0 = (unsigned char*)(ws + SA + SB);
  unsigned char* occ1 = occ0 + 16 * HM * WM;
  unsigned char* occ2 = occ1 + 8 * HM * WM;
  unsigned char* occ3 = occ2 + 4 * HM * WM;
  unsigned short* wb[8];
  {
    unsigned short* p = (unsigned short*)(occ3 + 2 * HM * WM);
    const int wsz[8] = {27 * 32 * 16, 27 * 64 * 32, 27 * 64 * 64, 27 * 64 * 64,
                        27 * 64 * 64, 27 * 64 * 64, 27 * 64 * 64, 27 * 64 * 64};
    for (int i = 0; i < 8; ++i) { wb[i] = p; p += wsz[i]; }
  }

  // scatter background (C=16 extent of xA) + occ masks must be zero each call
  hipMemsetAsync(xA, 0, (size_t)18 * 130 * 130 * 16 * 2, stream);
  hipMemsetAsync(occ0, 0, (size_t)(16 + 8 + 4 + 2) * HM * WM, stream);

  scatter_k<<<(npts + 255) / 256, 256, 0, stream>>>(vf, co, xA, occ0, occ1, occ2, occ3, npts);

  {
    int tot = 27 * (32 * 16 + 64 * 32 + 6 * 64 * 64);  // 732672, divisible by 256
    wcvt_all_k<<<tot / 256, 256, 0, stream>>>(
        (const float*)d_in[3], (const float*)d_in[4], (const float*)d_in[5],
        (const float*)d_in[6], (const float*)d_in[7], (const float*)d_in[8],
        (const float*)d_in[9], (const float*)d_in[10], wb[0]);
  }

  conv_k<16, 32, 32><<<16 * 64 + 64, 256, 0, stream>>>(xA, xB, wb[0], occ0, 16);
  conv_k<32, 64, 32><<<16 * 64 + 64, 256, 0, stream>>>(xB, xA, wb[1], occ0, 16);
  pool_sp_k<64><<<10 * HP, 256, 0, stream>>>(xA, xB, occ1, 8);
  conv_k<64, 64, 64><<<8 * 64 + 64, 256, 0, stream>>>(xB, xA, wb[2], occ1, 8);
  conv_k<64, 64, 64><<<8 * 64 + 64, 256, 0, stream>>>(xA, xB, wb[3], occ1, 8);
  conv_k<64, 64, 64><<<8 * 64 + 64, 256, 0, stream>>>(xB, xA, wb[4], occ1, 8);
  pool_sp_k<64><<<6 * HP, 256, 0, stream>>>(xA, xB, occ2, 4);
  conv_k<64, 64, 64><<<4 * 64 + 64, 256, 0, stream>>>(xB, xA, wb[5], occ2, 4);
  conv_k<64, 64, 64><<<4 * 64 + 64, 256, 0, stream>>>(xA, xB, wb[6], occ2, 4);
  conv_k<64, 64, 64><<<4 * 64 + 64, 256, 0, stream>>>(xB, xA, wb[7], occ2, 4);
  pool_d_k<<<(2 * 128 * 128 * 8) / 256, 256, 0, stream>>>(xA, (float*)d_out, occ3);
}